// Round 1
// baseline (147.373 us; speedup 1.0000x reference)
//
#include <hip/hip_runtime.h>
#include <math.h>

#define NB     8
#define BATCH  64
#define FEAT   512
#define HGT    1024
#define WHALF  513                 // W/2 + 1
#define PIX    (HGT * WHALF)       // 525312  (divisible by 4)
#define TOTAL  (BATCH * PIX)       // 33619968

// sqrtf(0.5f) exactly (f32 nearest of sqrt(0.5)); == reference's radius.max()
#define MAX_R  0x1.6A09E6p-1f

// ---------------------------------------------------------------------------
// Kernel 1: band_weights = softmax(freq_feat @ w.T + b)   -> bw[64][8] in ws
// ---------------------------------------------------------------------------
__global__ void bw_kernel(const float* __restrict__ ff,
                          const float* __restrict__ w,
                          const float* __restrict__ bias,
                          float* __restrict__ bw) {
    const int b = blockIdx.x;      // one block per batch row
    const int t = threadIdx.x;     // 256 threads

    float part[NB];
#pragma unroll
    for (int n = 0; n < NB; ++n) part[n] = 0.0f;

    for (int k = t; k < FEAT; k += 256) {
        float f = ff[b * FEAT + k];
#pragma unroll
        for (int n = 0; n < NB; ++n) part[n] += f * w[n * FEAT + k];
    }

    // wave (64-lane) reduction
#pragma unroll
    for (int n = 0; n < NB; ++n) {
#pragma unroll
        for (int off = 32; off > 0; off >>= 1)
            part[n] += __shfl_down(part[n], off);
    }

    __shared__ float red[4][NB];
    const int wave = t >> 6, lane = t & 63;
    if (lane == 0) {
#pragma unroll
        for (int n = 0; n < NB; ++n) red[wave][n] = part[n];
    }
    __syncthreads();

    if (t == 0) {
        float logit[NB], m = -1e30f;
#pragma unroll
        for (int n = 0; n < NB; ++n) {
            logit[n] = red[0][n] + red[1][n] + red[2][n] + red[3][n] + bias[n];
            m = fmaxf(m, logit[n]);
        }
        float s = 0.0f;
#pragma unroll
        for (int n = 0; n < NB; ++n) { logit[n] = expf(logit[n] - m); s += logit[n]; }
        const float inv = 1.0f / s;
#pragma unroll
        for (int n = 0; n < NB; ++n) bw[b * NB + n] = logit[n] * inv;
    }
}

// ---------------------------------------------------------------------------
// Band classification, bit-exact vs the numpy reference:
//   r2 = u*u + v*v is EXACT in f32 (k^2 + l^2 <= 2^19 fits the mantissa),
//   sqrtf is correctly rounded (no fast-math), boundaries use the identical
//   f32 expression max_r * (i/8).  Returns 8 for the single r == max_r pixel.
// ---------------------------------------------------------------------------
__device__ __forceinline__ int band_of(int p) {
    const int h  = p / WHALF;
    const int wp = p - h * WHALF;
    const float u = (float)wp * 0.0009765625f;                  // wp / 1024, exact
    const int hv  = (h >= 512) ? (h - 1024) : h;                // fftfreq numerator
    const float v = (float)hv * 0.0009765625f;                  // exact
    const float r = sqrtf(fmaf(u, u, v * v));                   // r2 exact -> r CR

    int j = (int)(r * (8.0f / MAX_R));                          // estimate
    if (j > 8) j = 8;
    const float lo = MAX_R * ((float)j * 0.125f);               // == ref lower[j]
    if (r < lo) {
        --j;
    } else if (j < 8) {
        const float hi = MAX_R * ((float)(j + 1) * 0.125f);     // == ref upper[j]
        if (r >= hi) ++j;
    }
    return j;                                                   // 0..7, or 8 = none
}

__global__ void band_kernel(unsigned char* __restrict__ band) {
    const int p = blockIdx.x * blockDim.x + threadIdx.x;
    if (p >= PIX) return;
    band[p] = (unsigned char)band_of(p);
}

// ---------------------------------------------------------------------------
// Kernel 3: out[b][p] = bw[b][band[p]]  (0 if band==8).  float4 stores.
// ---------------------------------------------------------------------------
__global__ void __launch_bounds__(256)
out_kernel(const float* __restrict__ bw,
           const unsigned char* __restrict__ band,
           float* __restrict__ out) {
    __shared__ float sbw[BATCH * NB + NB];   // +NB so index b*8+8 is safe
    for (int i = threadIdx.x; i < BATCH * NB + NB; i += blockDim.x)
        sbw[i] = (i < BATCH * NB) ? bw[i] : 0.0f;
    __syncthreads();

    const int nq = TOTAL / 4;
    const int stride = gridDim.x * blockDim.x;
    for (int q = blockIdx.x * blockDim.x + threadIdx.x; q < nq; q += stride) {
        const int base = q * 4;
        const int b = base / PIX;            // all 4 elts same batch (PIX % 4 == 0)
        const int p = base - b * PIX;
        const uchar4 j4 = *reinterpret_cast<const uchar4*>(band + p);
        const float* row = sbw + b * NB;
        float4 o;
        o.x = (j4.x < 8) ? row[j4.x] : 0.0f;
        o.y = (j4.y < 8) ? row[j4.y] : 0.0f;
        o.z = (j4.z < 8) ? row[j4.z] : 0.0f;
        o.w = (j4.w < 8) ? row[j4.w] : 0.0f;
        reinterpret_cast<float4*>(out)[q] = o;
    }
}

// Fallback if d_ws is too small for the band map: compute bands inline.
__global__ void __launch_bounds__(256)
out_fused_kernel(const float* __restrict__ bw, float* __restrict__ out) {
    __shared__ float sbw[BATCH * NB];
    for (int i = threadIdx.x; i < BATCH * NB; i += blockDim.x) sbw[i] = bw[i];
    __syncthreads();

    const int nq = TOTAL / 4;
    const int stride = gridDim.x * blockDim.x;
    for (int q = blockIdx.x * blockDim.x + threadIdx.x; q < nq; q += stride) {
        const int base = q * 4;
        const int b = base / PIX;
        const int p = base - b * PIX;
        const float* row = sbw + b * NB;
        float4 o;
        int j;
        j = band_of(p + 0); o.x = (j < 8) ? row[j] : 0.0f;
        j = band_of(p + 1); o.y = (j < 8) ? row[j] : 0.0f;
        j = band_of(p + 2); o.z = (j < 8) ? row[j] : 0.0f;
        j = band_of(p + 3); o.w = (j < 8) ? row[j] : 0.0f;
        reinterpret_cast<float4*>(out)[q] = o;
    }
}

extern "C" void kernel_launch(void* const* d_in, const int* in_sizes, int n_in,
                              void* d_out, int out_size, void* d_ws, size_t ws_size,
                              hipStream_t stream) {
    const float* ff   = (const float*)d_in[0];   // [64, 512]
    const float* w    = (const float*)d_in[1];   // [8, 512]
    const float* bias = (const float*)d_in[2];   // [8]
    float* out = (float*)d_out;                  // [64, 1, 1024, 513] f32

    float* bw = (float*)d_ws;                                    // 2048 B
    unsigned char* band = (unsigned char*)d_ws + 2048;           // 525312 B

    bw_kernel<<<BATCH, 256, 0, stream>>>(ff, w, bias, bw);

    if (ws_size >= 2048 + (size_t)PIX) {
        band_kernel<<<(PIX + 255) / 256, 256, 0, stream>>>(band);
        out_kernel<<<2048, 256, 0, stream>>>(bw, band, out);
    } else {
        out_fused_kernel<<<2048, 256, 0, stream>>>(bw, out);
    }
}